// Round 3
// baseline (1817.610 us; speedup 1.0000x reference)
//
#include <hip/hip_runtime.h>

typedef short bf16x8 __attribute__((ext_vector_type(8)));
typedef unsigned short u16x8 __attribute__((ext_vector_type(8)));
typedef unsigned short u16x4 __attribute__((ext_vector_type(4)));
typedef float f32x4 __attribute__((ext_vector_type(4)));
typedef unsigned short u16;

#define N_TOK 49
#define DIM   256
#define NWIN  1024
#define XS_S  264
#define QK_S  40
#define VT_S  72
#define P_S   72
#define OH_S  40

// bf16 workspace layout (u16 offsets)
#define WS_MASK_OFF   0ull
#define WS_QKVW_OFF   2458624ull                  // 1024*49*49
#define WS_PROJW_OFF  (WS_QKVW_OFF + 196608ull)   // 768*256
#define WS_QKVB_OFF   (WS_PROJW_OFF + 65536ull)   // 256*256
#define WS_PROJB_OFF  (WS_QKVB_OFF + 768ull)
#define WS_RPB_OFF    (WS_PROJB_OFF + 256ull)
#define WS_TOT_U16    (WS_RPB_OFF + 1352ull)      // 169*8 -> total 2,723,144 u16

__device__ __forceinline__ float bf2f(u16 b) {
  unsigned int u = ((unsigned int)b) << 16;
  return __builtin_bit_cast(float, u);
}
__device__ __forceinline__ u16 f2bf(float f) {
  unsigned int u = __builtin_bit_cast(unsigned int, f);
  return (u16)((u + 0x7fffu + ((u >> 16) & 1u)) >> 16);
}
__device__ __forceinline__ float lde(const void* p, size_t i, bool isbf) {
  return isbf ? bf2f(((const u16*)p)[i]) : ((const float*)p)[i];
}
__device__ __forceinline__ bf16x8 cvt8(const float* f) {
  f32x4 a = *(const f32x4*)f;
  f32x4 b = *(const f32x4*)(f + 4);
  u16x8 r;
  r[0]=f2bf(a[0]); r[1]=f2bf(a[1]); r[2]=f2bf(a[2]); r[3]=f2bf(a[3]);
  r[4]=f2bf(b[0]); r[5]=f2bf(b[1]); r[6]=f2bf(b[2]); r[7]=f2bf(b[3]);
  return __builtin_bit_cast(bf16x8, r);
}
// wave-uniform dtype probe: true if tensor looks like bf16
__device__ __forceinline__ bool probe_bf(const void* p) {
  int lane = threadIdx.x & 63;
  u16 h = ((const u16*)p)[2 * lane];
  int e = (h >> 7) & 0xFF;
  bool sane = ((h & 0x7fffu) == 0) || (e >= 96 && e <= 140);
  return (__ballot(!sane) == 0ull);
}

// ---- pre-pass: convert one float tensor (fp32 or bf16) to bf16 in ws ----
__global__ void cvt_kernel(const void* __restrict__ src, u16* __restrict__ dst, int n) {
  bool isbf = probe_bf(src);
  int i = blockIdx.x * 256 + threadIdx.x;
  if (i < n)
    dst[i] = isbf ? ((const u16*)src)[i] : f2bf(((const float*)src)[i]);
}

__global__ __launch_bounds__(256, 2)
void winattn_kernel(const void* __restrict__ x, const void* __restrict__ mask,
                    const void* __restrict__ qkv_w, const void* __restrict__ qkv_b,
                    const void* __restrict__ proj_w, const void* __restrict__ proj_b,
                    const void* __restrict__ rpb, const int* __restrict__ rel_idx,
                    void* __restrict__ out, const u16* __restrict__ wsu, int use_ws)
{
  __shared__ u16 xs [64 * XS_S];
  __shared__ u16 qs [64 * QK_S];
  __shared__ u16 ksm[64 * QK_S];
  __shared__ u16 vT [32 * VT_S];
  __shared__ u16 Ps [64 * P_S];
  __shared__ u16 oh [64 * OH_S];

  const int tid  = threadIdx.x;
  const int wv   = tid >> 6;
  const int lane = tid & 63;
  const int quad = lane >> 4;
  const int l15  = lane & 15;
  const int w    = blockIdx.x;

  // dtype probes (wave-uniform)
  const bool bx = probe_bf(x);
  bool bm0 = probe_bf(mask), bw0 = probe_bf(qkv_w), bqb0 = probe_bf(qkv_b),
       bpw0 = probe_bf(proj_w), bpb0 = probe_bf(proj_b), brp0 = probe_bf(rpb);

  // effective sources: bf16 workspace if available
  const void* mask_p = use_ws ? (const void*)(wsu + WS_MASK_OFF)  : mask;
  const void* qkvw_p = use_ws ? (const void*)(wsu + WS_QKVW_OFF)  : qkv_w;
  const void* qkvb_p = use_ws ? (const void*)(wsu + WS_QKVB_OFF)  : qkv_b;
  const void* pjw_p  = use_ws ? (const void*)(wsu + WS_PROJW_OFF) : proj_w;
  const void* pjb_p  = use_ws ? (const void*)(wsu + WS_PROJB_OFF) : proj_b;
  const void* rpb_p  = use_ws ? (const void*)(wsu + WS_RPB_OFF)   : rpb;
  const bool bm  = use_ws ? true : bm0;
  const bool bw  = use_ws ? true : bw0;
  const bool bqb = use_ws ? true : bqb0;
  const bool bpw = use_ws ? true : bpw0;
  const bool bpb = use_ws ? true : bpb0;
  const bool brp = use_ws ? true : brp0;

  // ---- stage x into LDS as bf16, zero rows 49..63 ----
  if (bx) {
    const u16* xw = (const u16*)x + (size_t)w * (N_TOK * DIM);
    for (int c = tid; c < (N_TOK * DIM / 8); c += 256) {
      int t = (c * 8) >> 8, col = (c * 8) & 255;
      *(u16x8*)&xs[t * XS_S + col] = ((const u16x8*)xw)[c];
    }
  } else {
    const float* xw = (const float*)x + (size_t)w * (N_TOK * DIM);
    for (int c = tid; c < (N_TOK * DIM / 8); c += 256) {
      int t = (c * 8) >> 8, col = (c * 8) & 255;
      *(u16x8*)&xs[t * XS_S + col] = __builtin_bit_cast(u16x8, cvt8(xw + c * 8));
    }
  }
  {
    u16x8 z = {0, 0, 0, 0, 0, 0, 0, 0};
    for (int c = tid; c < 495; c += 256)
      *(u16x8*)&xs[N_TOK * XS_S + c * 8] = z;
  }
  __syncthreads();

  f32x4 pacc[16];
  #pragma unroll
  for (int i = 0; i < 16; ++i) pacc[i] = (f32x4){0.f, 0.f, 0.f, 0.f};

  const int    mrow = 16 * wv + quad * 4;
  const size_t moff = (size_t)(w & (NWIN - 1)) * (N_TOK * N_TOK);

  #pragma unroll 1
  for (int h = 0; h < 8; ++h) {
    // ================= QKV GEMM =================
    f32x4 acc[6];
    #pragma unroll
    for (int j = 0; j < 6; ++j) acc[j] = (f32x4){0.f, 0.f, 0.f, 0.f};
    const int  nb0  = h * 32;
    const u16* arow = &xs[(16 * wv + l15) * XS_S + quad * 8];
    if (bw) {
      const u16* wp = (const u16*)qkvw_p;
      #pragma unroll
      for (int ks = 0; ks < 8; ++ks) {
        bf16x8 a = *(const bf16x8*)(arow + ks * 32);
        #pragma unroll
        for (int j = 0; j < 6; ++j) {
          int n = (j >> 1) * 256 + nb0 + (j & 1) * 16 + l15;
          bf16x8 b = *(const bf16x8*)(wp + (size_t)n * DIM + ks * 32 + quad * 8);
          acc[j] = __builtin_amdgcn_mfma_f32_16x16x32_bf16(a, b, acc[j], 0, 0, 0);
        }
      }
    } else {
      const float* wp = (const float*)qkvw_p;
      #pragma unroll
      for (int ks = 0; ks < 8; ++ks) {
        bf16x8 a = *(const bf16x8*)(arow + ks * 32);
        #pragma unroll
        for (int j = 0; j < 6; ++j) {
          int n = (j >> 1) * 256 + nb0 + (j & 1) * 16 + l15;
          bf16x8 b = cvt8(wp + (size_t)n * DIM + ks * 32 + quad * 8);
          acc[j] = __builtin_amdgcn_mfma_f32_16x16x32_bf16(a, b, acc[j], 0, 0, 0);
        }
      }
    }
    // write q (scaled,+bias), k (+bias), vT (+bias, transposed)
    {
      const float scale = 0.1767766952966369f;   // 1/sqrt(32)
      #pragma unroll
      for (int j = 0; j < 6; ++j) {
        int   n    = (j >> 1) * 256 + nb0 + (j & 1) * 16 + l15;
        float bias = lde(qkvb_p, n, bqb);
        int   lc   = (j & 1) * 16 + l15;
        if (j < 2) {
          #pragma unroll
          for (int r = 0; r < 4; ++r)
            qs[(mrow + r) * QK_S + lc] = f2bf((acc[j][r] + bias) * scale);
        } else if (j < 4) {
          #pragma unroll
          for (int r = 0; r < 4; ++r)
            ksm[(mrow + r) * QK_S + lc] = f2bf(acc[j][r] + bias);
        } else {
          u16x4 pk;
          #pragma unroll
          for (int r = 0; r < 4; ++r) pk[r] = f2bf(acc[j][r] + bias);
          *(u16x4*)&vT[lc * VT_S + mrow] = pk;
        }
      }
    }
    __syncthreads();

    // ================= S = q k^T =================
    f32x4 s[4];
    {
      bf16x8 aq = *(const bf16x8*)&qs[(16 * wv + l15) * QK_S + quad * 8];
      #pragma unroll
      for (int ni = 0; ni < 4; ++ni) {
        bf16x8 bk = *(const bf16x8*)&ksm[(ni * 16 + l15) * QK_S + quad * 8];
        s[ni] = __builtin_amdgcn_mfma_f32_16x16x32_bf16(aq, bk, (f32x4){0.f,0.f,0.f,0.f}, 0, 0, 0);
      }
    }
    // bias + mask + softmax (row = 16-lane quad-group)
    float rs[4];
    #pragma unroll
    for (int r = 0; r < 4; ++r) {
      int m = mrow + r;
      #pragma unroll
      for (int ni = 0; ni < 4; ++ni) {
        int   n = ni * 16 + l15;
        float v = s[ni][r];
        if (n >= N_TOK) {
          v = -1e30f;
        } else if (m < N_TOK) {
          int idx = rel_idx[m * N_TOK + n];
          v += lde(rpb_p, (size_t)idx * 8 + h, brp) + lde(mask_p, moff + m * N_TOK + n, bm);
        }
        s[ni][r] = v;
      }
      float mx = fmaxf(fmaxf(s[0][r], s[1][r]), fmaxf(s[2][r], s[3][r]));
      #pragma unroll
      for (int d2 = 1; d2 < 16; d2 <<= 1) mx = fmaxf(mx, __shfl_xor(mx, d2));
      float sum = 0.f;
      #pragma unroll
      for (int ni = 0; ni < 4; ++ni) {
        float p = __expf(s[ni][r] - mx);
        s[ni][r] = p;
        sum += p;
      }
      #pragma unroll
      for (int d2 = 1; d2 < 16; d2 <<= 1) sum += __shfl_xor(sum, d2);
      rs[r] = sum;
      #pragma unroll
      for (int ni = 0; ni < 4; ++ni)
        Ps[(mrow + r) * P_S + ni * 16 + l15] = f2bf(s[ni][r]);
    }

    // ================= O = P V =================
    f32x4 o0 = {0.f,0.f,0.f,0.f}, o1 = {0.f,0.f,0.f,0.f};
    #pragma unroll
    for (int ks = 0; ks < 2; ++ks) {
      bf16x8 ap = *(const bf16x8*)&Ps[(16 * wv + l15) * P_S + ks * 32 + quad * 8];
      bf16x8 b0 = *(const bf16x8*)&vT[(l15)      * VT_S + ks * 32 + quad * 8];
      bf16x8 b1 = *(const bf16x8*)&vT[(16 + l15) * VT_S + ks * 32 + quad * 8];
      o0 = __builtin_amdgcn_mfma_f32_16x16x32_bf16(ap, b0, o0, 0, 0, 0);
      o1 = __builtin_amdgcn_mfma_f32_16x16x32_bf16(ap, b1, o1, 0, 0, 0);
    }
    #pragma unroll
    for (int r = 0; r < 4; ++r) {
      float inv = 1.f / rs[r];
      oh[(mrow + r) * OH_S + l15]      = f2bf(o0[r] * inv);
      oh[(mrow + r) * OH_S + 16 + l15] = f2bf(o1[r] * inv);
    }

    // ================= proj partial =================
    {
      bf16x8 ao = *(const bf16x8*)&oh[(16 * wv + l15) * OH_S + quad * 8];
      if (bpw) {
        const u16* pp = (const u16*)pjw_p;
        #pragma unroll
        for (int ni = 0; ni < 16; ++ni) {
          bf16x8 bp = *(const bf16x8*)(pp + (size_t)(ni * 16 + l15) * DIM + h * 32 + quad * 8);
          pacc[ni] = __builtin_amdgcn_mfma_f32_16x16x32_bf16(ao, bp, pacc[ni], 0, 0, 0);
        }
      } else {
        const float* pp = (const float*)pjw_p;
        #pragma unroll
        for (int ni = 0; ni < 16; ++ni) {
          bf16x8 bp = cvt8(pp + (size_t)(ni * 16 + l15) * DIM + h * 32 + quad * 8);
          pacc[ni] = __builtin_amdgcn_mfma_f32_16x16x32_bf16(ao, bp, pacc[ni], 0, 0, 0);
        }
      }
    }
    __syncthreads();
  }

  // ================= epilogue: + proj_b; output dtype follows x =================
  const size_t obase = (size_t)w * (N_TOK * DIM);
  if (bx) {
    u16* ow = (u16*)out + obase;
    #pragma unroll
    for (int r = 0; r < 4; ++r) {
      int m = mrow + r;
      if (m < N_TOK) {
        #pragma unroll
        for (int ni = 0; ni < 16; ++ni) {
          int col = ni * 16 + l15;
          ow[m * DIM + col] = f2bf(pacc[ni][r] + lde(pjb_p, col, bpb));
        }
      }
    }
  } else {
    float* ow = (float*)out + obase;
    #pragma unroll
    for (int r = 0; r < 4; ++r) {
      int m = mrow + r;
      if (m < N_TOK) {
        #pragma unroll
        for (int ni = 0; ni < 16; ++ni) {
          int col = ni * 16 + l15;
          ow[m * DIM + col] = pacc[ni][r] + lde(pjb_p, col, bpb);
        }
      }
    }
  }
}

extern "C" void kernel_launch(void* const* d_in, const int* in_sizes, int n_in,
                              void* d_out, int out_size, void* d_ws, size_t ws_size,
                              hipStream_t stream) {
  const int use_ws = (ws_size >= WS_TOT_U16 * 2) ? 1 : 0;
  u16* wsu = (u16*)d_ws;
  if (use_ws) {
    auto cv = [&](const void* src, unsigned long long off, int n) {
      cvt_kernel<<<(n + 255) / 256, 256, 0, stream>>>(src, wsu + off, n);
    };
    cv(d_in[1], WS_MASK_OFF,  NWIN * N_TOK * N_TOK);
    cv(d_in[2], WS_QKVW_OFF,  3 * DIM * DIM);
    cv(d_in[3], WS_QKVB_OFF,  3 * DIM);
    cv(d_in[4], WS_PROJW_OFF, DIM * DIM);
    cv(d_in[5], WS_PROJB_OFF, DIM);
    cv(d_in[6], WS_RPB_OFF,   169 * 8);
  }
  winattn_kernel<<<4096, 256, 0, stream>>>(
      d_in[0], d_in[1], d_in[2], d_in[3], d_in[4], d_in[5], d_in[6],
      (const int*)d_in[7], d_out, wsu, use_ws);
}